// Round 3
// baseline (13868.256 us; speedup 1.0000x reference)
//
#include <hip/hip_runtime.h>

#define NN 100000
#define EE 600000
#define FIN 39
#define HD 128

// ---------------- input projection: h = relu(x @ W_in + b_in), pure fp32 ----------------
__global__ __launch_bounds__(256) void k_input_proj(
    const float* __restrict__ x, const float* __restrict__ Wi,
    const float* __restrict__ bi, float* __restrict__ h)
{
    __shared__ float Ws[FIN * HD];
    __shared__ float xs[16][FIN + 1];
    int tid = threadIdx.x;
    for (int i = tid; i < FIN * HD; i += 256) Ws[i] = Wi[i];
    int base = blockIdx.x * 16;
    for (int i = tid; i < 16 * FIN; i += 256) {
        int nd = i / FIN, k = i - nd * FIN;
        xs[nd][k] = x[(size_t)(base + nd) * FIN + k];
    }
    __syncthreads();
    int j = tid & 127, slot = tid >> 7;
    float bj = bi[j];
    for (int r = 0; r < 8; ++r) {
        int nd = slot * 8 + r;
        float acc = bj;
#pragma unroll
        for (int k = 0; k < FIN; ++k) acc += xs[nd][k] * Ws[k * HD + j];
        h[(size_t)(base + nd) * HD + j] = fmaxf(acc, 0.f);
    }
}

// ---------------- literal edge conv ----------------
// one edge per 128 threads (2 edges per 256-thread block):
//   m = [h[tgt] | h[src] | ea]  (258)
//   z = relu(m @ W1 + b1)       (128)
//   o = z @ W2 + b2             (128)
//   agg[tgt] += o               (atomic, fp32)
__global__ __launch_bounds__(256) void k_edge_simple(
    const float* __restrict__ h, const int* __restrict__ ei,
    const float* __restrict__ ea,
    const float* __restrict__ W1, const float* __restrict__ b1,
    const float* __restrict__ W2, const float* __restrict__ b2,
    float* __restrict__ agg)
{
    __shared__ float m_s[2][2 * HD + 2];
    __shared__ float z_s[2][HD];
    int tid = threadIdx.x;
    int el = tid >> 7, j = tid & 127;
    int eg = blockIdx.x * 2 + el;
    int src = ei[eg];
    int tgt = ei[EE + eg];
    m_s[el][j]      = h[(size_t)tgt * HD + j];   // x_i = target features, k 0..127
    m_s[el][HD + j] = h[(size_t)src * HD + j];   // x_j = source features, k 128..255
    if (j < 2) m_s[el][2 * HD + j] = ea[2 * eg + j];
    __syncthreads();

    float acc = b1[j];
    for (int k = 0; k < 2 * HD + 2; ++k) acc += m_s[el][k] * W1[k * HD + j];
    z_s[el][j] = fmaxf(acc, 0.f);
    __syncthreads();

    float o = b2[j];
    for (int k = 0; k < HD; ++k) o += z_s[el][k] * W2[k * HD + j];
    atomicAdd(&agg[(size_t)tgt * HD + j], o);
}

// ---------------- node post: t = h + agg; u = LN(t); h = u + relu(u @ cW + cb) ----------------
__global__ __launch_bounds__(128) void k_post(
    float* __restrict__ h, const float* __restrict__ agg,
    const float* __restrict__ g, const float* __restrict__ bln,
    const float* __restrict__ cW, const float* __restrict__ cb)
{
    __shared__ float u_s[HD];
    __shared__ float red[HD], red2[HD];
    int j = threadIdx.x;
    size_t go = (size_t)blockIdx.x * HD;
    float t = h[go + j] + agg[go + j];
    red[j] = t; red2[j] = t * t;
    __syncthreads();
    for (int s = 64; s > 0; s >>= 1) {
        if (j < s) { red[j] += red[j + s]; red2[j] += red2[j + s]; }
        __syncthreads();
    }
    float mu = red[0] * (1.f / HD);
    float var = red2[0] * (1.f / HD) - mu * mu;
    float inv = rsqrtf(var + 1e-5f);
    float u = (t - mu) * inv * g[j] + bln[j];
    u_s[j] = u;
    __syncthreads();
    float c = cb[j];
    for (int k = 0; k < HD; ++k) c += u_s[k] * cW[k * HD + j];
    h[go + j] = u + fmaxf(c, 0.f);
}

extern "C" void kernel_launch(void* const* d_in, const int* in_sizes, int n_in,
                              void* d_out, int out_size, void* d_ws, size_t ws_size,
                              hipStream_t stream) {
    const float* x    = (const float*)d_in[0];
    const int*   a_ei = (const int*)d_in[1];
    const float* a_ea = (const float*)d_in[2];
    const int*   e_ei = (const int*)d_in[3];
    const float* e_ea = (const float*)d_in[4];
    const float* W_in = (const float*)d_in[5];
    const float* b_in = (const float*)d_in[6];
    const float* aW1  = (const float*)d_in[7];
    const float* ab1  = (const float*)d_in[8];
    const float* aW2  = (const float*)d_in[9];
    const float* ab2  = (const float*)d_in[10];
    const float* eW1  = (const float*)d_in[11];
    const float* eb1  = (const float*)d_in[12];
    const float* eW2  = (const float*)d_in[13];
    const float* eb2  = (const float*)d_in[14];
    const float* ln_g = (const float*)d_in[15];
    const float* ln_b = (const float*)d_in[16];
    const float* cW   = (const float*)d_in[17];
    const float* cb   = (const float*)d_in[18];
    float* h = (float*)d_out;

    float* agg = (float*)d_ws;   // NN*HD floats = 51.2 MB

    k_input_proj<<<NN / 16, 256, 0, stream>>>(x, W_in, b_in, h);

    for (int l = 0; l < 2; ++l) {
        hipMemsetAsync(agg, 0, (size_t)NN * HD * 4, stream);
        k_edge_simple<<<EE / 2, 256, 0, stream>>>(
            h, a_ei, a_ea,
            aW1 + (size_t)l * (2 * HD + 2) * HD, ab1 + l * HD,
            aW2 + (size_t)l * HD * HD,           ab2 + l * HD, agg);
        k_edge_simple<<<EE / 2, 256, 0, stream>>>(
            h, e_ei, e_ea,
            eW1 + (size_t)l * (2 * HD + 2) * HD, eb1 + l * HD,
            eW2 + (size_t)l * HD * HD,           eb2 + l * HD, agg);
        k_post<<<NN, 128, 0, stream>>>(h, agg, ln_g + l * HD, ln_b + l * HD,
                                       cW + (size_t)l * HD * HD, cb + l * HD);
    }
}

// Round 4
// 1695.313 us; speedup vs baseline: 8.1804x; 8.1804x over previous
//
#include <hip/hip_runtime.h>

#define NN 100000
#define EE 600000
#define FIN 39
#define HD 128
#define K1 256          // edge GEMM K (ea handled separately in fp32)
#define MROW 264        // LDS row stride (fp16 elems)
#define LOSCALE 4096.0f
#define INV_LOSCALE (1.0f / 4096.0f)

typedef _Float16 f16x8 __attribute__((ext_vector_type(8)));
typedef __attribute__((ext_vector_type(4))) float f32x4;

#define MFMA16(a, b, c) __builtin_amdgcn_mfma_f32_16x16x32_f16((a), (b), (c), 0, 0, 0)

__device__ __forceinline__ void split_hl(float x, unsigned short& hi, unsigned short& lo) {
    union { _Float16 h; unsigned short u; } a, b;
    a.h = (_Float16)x;
    float r = (x - (float)a.h) * LOSCALE;   // scaled residual stays fp16-normal
    b.h = (_Float16)r;
    hi = a.u; lo = b.u;
}

// ---------------- input projection: h = relu(x @ W_in + b_in), fp32; emit hi/lo ----------------
__global__ __launch_bounds__(256) void k_input_proj(
    const float* __restrict__ x, const float* __restrict__ Wi,
    const float* __restrict__ bi, float* __restrict__ h,
    unsigned short* __restrict__ hhi, unsigned short* __restrict__ hlo)
{
    __shared__ float Ws[FIN * HD];
    __shared__ float xs[16][FIN + 1];
    int tid = threadIdx.x;
    for (int i = tid; i < FIN * HD; i += 256) Ws[i] = Wi[i];
    int base = blockIdx.x * 16;
    for (int i = tid; i < 16 * FIN; i += 256) {
        int nd = i / FIN, k = i - nd * FIN;
        xs[nd][k] = x[(size_t)(base + nd) * FIN + k];
    }
    __syncthreads();
    int j = tid & 127, slot = tid >> 7;
    float bj = bi[j];
    for (int r = 0; r < 8; ++r) {
        int nd = slot * 8 + r;
        float acc = bj;
#pragma unroll
        for (int k = 0; k < FIN; ++k) acc += xs[nd][k] * Ws[k * HD + j];
        acc = fmaxf(acc, 0.f);
        int o = (base + nd) * HD + j;
        h[o] = acc;
        unsigned short hv, lv; split_hl(acc, hv, lv);
        hhi[o] = hv; hlo[o] = lv;
    }
}

// ---------------- degree count ----------------
__global__ __launch_bounds__(256) void k_deg(const int* __restrict__ ei, float* __restrict__ deg) {
    int e = blockIdx.x * 256 + threadIdx.x;
    if (e < EE) atomicAdd(&deg[ei[EE + e]], 1.0f);
}

// ---------------- W1 [258][128] -> hi/lo [128][256] (n-major, rows 256/257 excluded) ----------------
__global__ __launch_bounds__(256) void k_prep_w1(const float* __restrict__ W,
                                                 unsigned short* __restrict__ Whi,
                                                 unsigned short* __restrict__ Wlo) {
    int i = blockIdx.x * 256 + threadIdx.x;
    if (i >= HD * K1) return;
    int n = i >> 8, k = i & 255;
    unsigned short hv, lv; split_hl(W[k * HD + n], hv, lv);
    Whi[i] = hv; Wlo[i] = lv;
}

// ---------------- [W2a;W2e] -> hi/lo [128][256] ----------------
__global__ __launch_bounds__(256) void k_prep_w2(const float* __restrict__ Wa, const float* __restrict__ We,
                                                 unsigned short* __restrict__ Whi,
                                                 unsigned short* __restrict__ Wlo) {
    int i = blockIdx.x * 256 + threadIdx.x;
    if (i >= HD * 256) return;
    int n = i >> 8, k = i & 255;
    float v = (k < HD) ? Wa[k * HD + n] : We[(k - HD) * HD + n];
    unsigned short hv, lv; split_hl(v, hv, lv);
    Whi[i] = hv; Wlo[i] = lv;
}

// ---------------- comb_W [128][128] -> hi/lo [128][128] transposed ----------------
__global__ __launch_bounds__(256) void k_prep_cw(const float* __restrict__ W,
                                                 unsigned short* __restrict__ Whi,
                                                 unsigned short* __restrict__ Wlo) {
    int i = blockIdx.x * 256 + threadIdx.x;
    if (i >= HD * HD) return;
    int n = i >> 7, k = i & 127;
    unsigned short hv, lv; split_hl(W[k * HD + n], hv, lv);
    Whi[i] = hv; Wlo[i] = lv;
}

// ---------------- edge conv (hi/lo MFMA): zagg[t] += relu([h_t|h_s|ea] @ W1 + b1) ----------------
__global__ __launch_bounds__(256) void k_edge(
    const unsigned short* __restrict__ hhi, const unsigned short* __restrict__ hlo,
    const int* __restrict__ ei, const float* __restrict__ ea,
    const unsigned short* __restrict__ Whi, const unsigned short* __restrict__ Wlo,
    const float* __restrict__ W1full,     // original [258][128] fp32 for rows 256/257
    const float* __restrict__ b1,
    float* __restrict__ zagg)
{
    __shared__ unsigned short m_hi[16][MROW];
    __shared__ unsigned short m_lo[16][MROW];
    __shared__ int   ts_s[16];
    __shared__ float ea_s[2][16];
    int tid = threadIdx.x;
    int wave = tid >> 6, lane = tid & 63;
    int l16 = lane & 15, quad = lane >> 4;
    int nb0 = wave * 2;
    int n0 = nb0 * 16 + l16, n1 = n0 + 16;

    // persistent B fragments, hi and (scaled) lo
    f16x8 bhi[2][8], blo[2][8];
#pragma unroll
    for (int b = 0; b < 2; ++b) {
        int n = (nb0 + b) * 16 + l16;
        const unsigned short* ph = Whi + n * K1 + quad * 8;
        const unsigned short* pl = Wlo + n * K1 + quad * 8;
#pragma unroll
        for (int kt = 0; kt < 8; ++kt) {
            bhi[b][kt] = *(const f16x8*)(ph + kt * 32);
            blo[b][kt] = *(const f16x8*)(pl + kt * 32);
        }
    }
    float bias0 = b1[n0], bias1 = b1[n1];
    float w256_0 = W1full[256 * HD + n0], w257_0 = W1full[257 * HD + n0];
    float w256_1 = W1full[256 * HD + n1], w257_1 = W1full[257 * HD + n1];

    int le = tid >> 4, part = tid & 15;

    for (int tile = blockIdx.x; tile < EE / 16; tile += gridDim.x) {
        __syncthreads();   // prev-iteration readers done
        int eg = tile * 16 + le;
        int src = ei[eg];
        int tgt = ei[EE + eg];
        if (part == 0) {
            ts_s[le] = tgt;
            ea_s[0][le] = ea[2 * eg];
            ea_s[1][le] = ea[2 * eg + 1];
        }
        size_t rb = (size_t)((part < 8) ? tgt : src) * HD + (part & 7) * 16;
        uint4 h0 = *(const uint4*)(hhi + rb);
        uint4 h1 = *(const uint4*)(hhi + rb + 8);
        uint4 l0 = *(const uint4*)(hlo + rb);
        uint4 l1 = *(const uint4*)(hlo + rb + 8);
        int ko = part * 16;
        *(uint4*)&m_hi[le][ko] = h0; *(uint4*)&m_hi[le][ko + 8] = h1;
        *(uint4*)&m_lo[le][ko] = l0; *(uint4*)&m_lo[le][ko + 8] = l1;
        __syncthreads();

        f32x4 acc0 = {0,0,0,0}, acc1 = {0,0,0,0};
        f32x4 accL0 = {0,0,0,0}, accL1 = {0,0,0,0};
#pragma unroll
        for (int kt = 0; kt < 8; ++kt) {
            f16x8 ah = *(const f16x8*)&m_hi[l16][kt * 32 + quad * 8];
            f16x8 al = *(const f16x8*)&m_lo[l16][kt * 32 + quad * 8];
            acc0  = MFMA16(ah, bhi[0][kt], acc0);
            acc1  = MFMA16(ah, bhi[1][kt], acc1);
            accL0 = MFMA16(ah, blo[0][kt], accL0);
            accL1 = MFMA16(ah, blo[1][kt], accL1);
            accL0 = MFMA16(al, bhi[0][kt], accL0);
            accL1 = MFMA16(al, bhi[1][kt], accL1);
        }

#pragma unroll
        for (int r = 0; r < 4; ++r) {
            int e = quad * 4 + r;
            int t = ts_s[e];
            float e0 = ea_s[0][e], e1 = ea_s[1][e];
            float z0 = acc0[r] + accL0[r] * INV_LOSCALE + bias0 + e0 * w256_0 + e1 * w257_0;
            float z1 = acc1[r] + accL1[r] * INV_LOSCALE + bias1 + e0 * w256_1 + e1 * w257_1;
            z0 = fmaxf(z0, 0.f); z1 = fmaxf(z1, 0.f);
            float* zp = zagg + (size_t)t * HD;
            atomicAdd(zp + n0, z0);
            atomicAdd(zp + n1, z1);
        }
    }
}

// ---------------- node update (hi/lo MFMA):
// t = h + za@W2a + da*b2a + ze@W2e + de*b2e; u = LN(t); h' = u + relu(u@cW + cb)
__global__ __launch_bounds__(256) void k_node(
    float* __restrict__ h,
    unsigned short* __restrict__ hhi, unsigned short* __restrict__ hlo,
    const float* __restrict__ za, const float* __restrict__ ze,
    const float* __restrict__ da, const float* __restrict__ de,
    const unsigned short* __restrict__ W2hi, const unsigned short* __restrict__ W2lo, // [128][256]
    const float* __restrict__ b2a, const float* __restrict__ b2e,
    const float* __restrict__ g, const float* __restrict__ bln,
    const unsigned short* __restrict__ cWhi, const unsigned short* __restrict__ cWlo, // [128][128]
    const float* __restrict__ cb)
{
    __shared__ unsigned short a_hi[16][MROW], a_lo[16][MROW];
    __shared__ float t1_s[16][132];
    __shared__ unsigned short u_hi[16][136], u_lo[16][136];
    __shared__ float g_s[HD], b_s[HD];
    int tid = threadIdx.x;
    int wave = tid >> 6, lane = tid & 63;
    int l16 = lane & 15, quad = lane >> 4;
    int nb0 = wave * 2;
    int n0 = nb0 * 16 + l16, n1 = n0 + 16;

    if (tid < HD) { g_s[tid] = g[tid]; b_s[tid] = bln[tid]; }

    f16x8 b2h[2][8], b2l[2][8], bch[2][4], bcl[2][4];
#pragma unroll
    for (int b = 0; b < 2; ++b) {
        int n = (nb0 + b) * 16 + l16;
        const unsigned short* p2h = W2hi + n * 256 + quad * 8;
        const unsigned short* p2l = W2lo + n * 256 + quad * 8;
#pragma unroll
        for (int kt = 0; kt < 8; ++kt) {
            b2h[b][kt] = *(const f16x8*)(p2h + kt * 32);
            b2l[b][kt] = *(const f16x8*)(p2l + kt * 32);
        }
        const unsigned short* pch = cWhi + n * 128 + quad * 8;
        const unsigned short* pcl = cWlo + n * 128 + quad * 8;
#pragma unroll
        for (int kt = 0; kt < 4; ++kt) {
            bch[b][kt] = *(const f16x8*)(pch + kt * 32);
            bcl[b][kt] = *(const f16x8*)(pcl + kt * 32);
        }
    }
    float vb2a0 = b2a[n0], vb2a1 = b2a[n1];
    float vb2e0 = b2e[n0], vb2e1 = b2e[n1];
    float vcb0 = cb[n0], vcb1 = cb[n1];

    int base = blockIdx.x * 16;
    int nd = tid >> 4, part = tid & 15;

    // stage A = hi/lo([za | ze]) for 16 nodes
    {
        const float* sp = ((part < 8) ? za : ze) + (size_t)(base + nd) * HD + (part & 7) * 16;
        union { unsigned short s[16]; uint4 q[2]; } Hv, Lv;
#pragma unroll
        for (int i = 0; i < 4; ++i) {
            float4 f = ((const float4*)sp)[i];
            split_hl(f.x, Hv.s[4*i+0], Lv.s[4*i+0]);
            split_hl(f.y, Hv.s[4*i+1], Lv.s[4*i+1]);
            split_hl(f.z, Hv.s[4*i+2], Lv.s[4*i+2]);
            split_hl(f.w, Hv.s[4*i+3], Lv.s[4*i+3]);
        }
        int ko = part * 16;
        *(uint4*)&a_hi[nd][ko] = Hv.q[0]; *(uint4*)&a_hi[nd][ko + 8] = Hv.q[1];
        *(uint4*)&a_lo[nd][ko] = Lv.q[0]; *(uint4*)&a_lo[nd][ko + 8] = Lv.q[1];
    }
    __syncthreads();

    // GEMM1: K=256
    f32x4 acc0 = {0,0,0,0}, acc1 = {0,0,0,0}, accL0 = {0,0,0,0}, accL1 = {0,0,0,0};
#pragma unroll
    for (int kt = 0; kt < 8; ++kt) {
        f16x8 ah = *(const f16x8*)&a_hi[l16][kt * 32 + quad * 8];
        f16x8 al = *(const f16x8*)&a_lo[l16][kt * 32 + quad * 8];
        acc0  = MFMA16(ah, b2h[0][kt], acc0);
        acc1  = MFMA16(ah, b2h[1][kt], acc1);
        accL0 = MFMA16(ah, b2l[0][kt], accL0);
        accL1 = MFMA16(ah, b2l[1][kt], accL1);
        accL0 = MFMA16(al, b2h[0][kt], accL0);
        accL1 = MFMA16(al, b2h[1][kt], accL1);
    }
#pragma unroll
    for (int r = 0; r < 4; ++r) {
        int ndl = quad * 4 + r;
        int go = (base + ndl) * HD;
        float dav = da[base + ndl], dev = de[base + ndl];
        t1_s[ndl][n0] = acc0[r] + accL0[r] * INV_LOSCALE + h[go + n0] + dav * vb2a0 + dev * vb2e0;
        t1_s[ndl][n1] = acc1[r] + accL1[r] * INV_LOSCALE + h[go + n1] + dav * vb2a1 + dev * vb2e1;
    }
    __syncthreads();

    // LayerNorm
    float v[8]; float s = 0.f, ss = 0.f;
#pragma unroll
    for (int i = 0; i < 8; ++i) { v[i] = t1_s[nd][part * 8 + i]; s += v[i]; ss += v[i] * v[i]; }
#pragma unroll
    for (int m = 1; m < 16; m <<= 1) { s += __shfl_xor(s, m); ss += __shfl_xor(ss, m); }
    float mu = s * (1.f / HD);
    float var = ss * (1.f / HD) - mu * mu;
    float inv = rsqrtf(var + 1e-5f);
    {
        union { unsigned short s[8]; uint4 q; } Hu, Lu;
#pragma unroll
        for (int i = 0; i < 8; ++i) {
            int c = part * 8 + i;
            float u = (v[i] - mu) * inv * g_s[c] + b_s[c];
            t1_s[nd][c] = u;
            split_hl(u, Hu.s[i], Lu.s[i]);
        }
        *(uint4*)&u_hi[nd][part * 8] = Hu.q;
        *(uint4*)&u_lo[nd][part * 8] = Lu.q;
    }
    __syncthreads();

    // GEMM2: K=128 (comb)
    f32x4 c0 = {0,0,0,0}, c1 = {0,0,0,0}, cL0 = {0,0,0,0}, cL1 = {0,0,0,0};
#pragma unroll
    for (int kt = 0; kt < 4; ++kt) {
        f16x8 ah = *(const f16x8*)&u_hi[l16][kt * 32 + quad * 8];
        f16x8 al = *(const f16x8*)&u_lo[l16][kt * 32 + quad * 8];
        c0  = MFMA16(ah, bch[0][kt], c0);
        c1  = MFMA16(ah, bch[1][kt], c1);
        cL0 = MFMA16(ah, bcl[0][kt], cL0);
        cL1 = MFMA16(ah, bcl[1][kt], cL1);
        cL0 = MFMA16(al, bch[0][kt], cL0);
        cL1 = MFMA16(al, bch[1][kt], cL1);
    }
#pragma unroll
    for (int r = 0; r < 4; ++r) {
        int ndl = quad * 4 + r;
        int go = (base + ndl) * HD;
        float u0 = t1_s[ndl][n0], u1 = t1_s[ndl][n1];
        float r0 = fmaxf(c0[r] + cL0[r] * INV_LOSCALE + vcb0, 0.f);
        float r1 = fmaxf(c1[r] + cL1[r] * INV_LOSCALE + vcb1, 0.f);
        float o0 = u0 + r0, o1 = u1 + r1;
        h[go + n0] = o0; h[go + n1] = o1;
        unsigned short hv, lv;
        split_hl(o0, hv, lv); hhi[go + n0] = hv; hlo[go + n0] = lv;
        split_hl(o1, hv, lv); hhi[go + n1] = hv; hlo[go + n1] = lv;
    }
}

extern "C" void kernel_launch(void* const* d_in, const int* in_sizes, int n_in,
                              void* d_out, int out_size, void* d_ws, size_t ws_size,
                              hipStream_t stream) {
    const float* x    = (const float*)d_in[0];
    const int*   a_ei = (const int*)d_in[1];
    const float* a_ea = (const float*)d_in[2];
    const int*   e_ei = (const int*)d_in[3];
    const float* e_ea = (const float*)d_in[4];
    const float* W_in = (const float*)d_in[5];
    const float* b_in = (const float*)d_in[6];
    const float* aW1  = (const float*)d_in[7];
    const float* ab1  = (const float*)d_in[8];
    const float* aW2  = (const float*)d_in[9];
    const float* ab2  = (const float*)d_in[10];
    const float* eW1  = (const float*)d_in[11];
    const float* eb1  = (const float*)d_in[12];
    const float* eW2  = (const float*)d_in[13];
    const float* eb2  = (const float*)d_in[14];
    const float* ln_g = (const float*)d_in[15];
    const float* ln_b = (const float*)d_in[16];
    const float* cW   = (const float*)d_in[17];
    const float* cb   = (const float*)d_in[18];
    float* h = (float*)d_out;

    char* ws = (char*)d_ws;
    unsigned short* W1thi = (unsigned short*)ws; ws += (size_t)4 * HD * K1 * 2;
    unsigned short* W1tlo = (unsigned short*)ws; ws += (size_t)4 * HD * K1 * 2;
    unsigned short* W2thi = (unsigned short*)ws; ws += (size_t)2 * HD * 256 * 2;
    unsigned short* W2tlo = (unsigned short*)ws; ws += (size_t)2 * HD * 256 * 2;
    unsigned short* cWthi = (unsigned short*)ws; ws += (size_t)2 * HD * HD * 2;
    unsigned short* cWtlo = (unsigned short*)ws; ws += (size_t)2 * HD * HD * 2;
    float* da = (float*)ws;                      ws += (size_t)NN * 4;
    float* de = (float*)ws;                      ws += (size_t)NN * 4;
    unsigned short* hhi = (unsigned short*)ws;   ws += (size_t)NN * HD * 2;
    unsigned short* hlo = (unsigned short*)ws;   ws += (size_t)NN * HD * 2;
    float* zagg_a = (float*)ws;                  ws += (size_t)NN * HD * 4;
    float* zagg_e = (float*)ws;                  ws += (size_t)NN * HD * 4;

    k_input_proj<<<NN / 16, 256, 0, stream>>>(x, W_in, b_in, h, hhi, hlo);

    hipMemsetAsync(da, 0, (size_t)NN * 4, stream);
    hipMemsetAsync(de, 0, (size_t)NN * 4, stream);
    k_deg<<<(EE + 255) / 256, 256, 0, stream>>>(a_ei, da);
    k_deg<<<(EE + 255) / 256, 256, 0, stream>>>(e_ei, de);

    int gw1 = (HD * K1 + 255) / 256;
    const int W1SZ = (2 * HD + 2) * HD;   // 258*128 per layer
    k_prep_w1<<<gw1, 256, 0, stream>>>(aW1,        W1thi + 0 * HD * K1, W1tlo + 0 * HD * K1);
    k_prep_w1<<<gw1, 256, 0, stream>>>(aW1 + W1SZ, W1thi + 1 * HD * K1, W1tlo + 1 * HD * K1);
    k_prep_w1<<<gw1, 256, 0, stream>>>(eW1,        W1thi + 2 * HD * K1, W1tlo + 2 * HD * K1);
    k_prep_w1<<<gw1, 256, 0, stream>>>(eW1 + W1SZ, W1thi + 3 * HD * K1, W1tlo + 3 * HD * K1);
    for (int l = 0; l < 2; ++l) {
        k_prep_w2<<<(HD * 256 + 255) / 256, 256, 0, stream>>>(
            aW2 + (size_t)l * HD * HD, eW2 + (size_t)l * HD * HD,
            W2thi + l * HD * 256, W2tlo + l * HD * 256);
        k_prep_cw<<<(HD * HD + 255) / 256, 256, 0, stream>>>(
            cW + (size_t)l * HD * HD, cWthi + l * HD * HD, cWtlo + l * HD * HD);
    }

    for (int l = 0; l < 2; ++l) {
        hipMemsetAsync(zagg_a, 0, (size_t)NN * HD * 4, stream);
        hipMemsetAsync(zagg_e, 0, (size_t)NN * HD * 4, stream);
        k_edge<<<4096, 256, 0, stream>>>(hhi, hlo, a_ei, a_ea,
            W1thi + (0 + l) * HD * K1, W1tlo + (0 + l) * HD * K1,
            aW1 + (size_t)l * W1SZ, ab1 + l * HD, zagg_a);
        k_edge<<<4096, 256, 0, stream>>>(hhi, hlo, e_ei, e_ea,
            W1thi + (2 + l) * HD * K1, W1tlo + (2 + l) * HD * K1,
            eW1 + (size_t)l * W1SZ, eb1 + l * HD, zagg_e);
        k_node<<<NN / 16, 256, 0, stream>>>(h, hhi, hlo, zagg_a, zagg_e, da, de,
            W2thi + l * HD * 256, W2tlo + l * HD * 256, ab2 + l * HD, eb2 + l * HD,
            ln_g + l * HD, ln_b + l * HD,
            cWthi + l * HD * HD, cWtlo + l * HD * HD, cb + l * HD);
    }
}

// Round 5
// 1607.177 us; speedup vs baseline: 8.6290x; 1.0548x over previous
//
#include <hip/hip_runtime.h>

#define NN 100000
#define EE 600000
#define FIN 39
#define HD 128
#define K1 256          // edge GEMM K (ea handled separately in fp32)
#define LOSCALE 4096.0f
#define INV_LOSCALE (1.0f / 4096.0f)
#define SCB 98          // scan blocks per graph: 98*1024 >= NN

typedef _Float16 f16x8 __attribute__((ext_vector_type(8)));
typedef __attribute__((ext_vector_type(4))) float f32x4;

#define MFMA16(a, b, c) __builtin_amdgcn_mfma_f32_16x16x32_f16((a), (b), (c), 0, 0, 0)

__device__ __forceinline__ void split_hl(float x, unsigned short& hi, unsigned short& lo) {
    union { _Float16 h; unsigned short u; } a, b;
    a.h = (_Float16)x;
    float r = (x - (float)a.h) * LOSCALE;   // scaled residual stays fp16-normal
    b.h = (_Float16)r;
    hi = a.u; lo = b.u;
}

// ---------------- input projection: h = relu(x @ W_in + b_in), fp32; emit hi/lo ----------------
__global__ __launch_bounds__(256) void k_input_proj(
    const float* __restrict__ x, const float* __restrict__ Wi,
    const float* __restrict__ bi, float* __restrict__ h,
    unsigned short* __restrict__ hhi, unsigned short* __restrict__ hlo)
{
    __shared__ float Ws[FIN * HD];
    __shared__ float xs[16][FIN + 1];
    int tid = threadIdx.x;
    for (int i = tid; i < FIN * HD; i += 256) Ws[i] = Wi[i];
    int base = blockIdx.x * 16;
    for (int i = tid; i < 16 * FIN; i += 256) {
        int nd = i / FIN, k = i - nd * FIN;
        xs[nd][k] = x[(size_t)(base + nd) * FIN + k];
    }
    __syncthreads();
    int j = tid & 127, slot = tid >> 7;
    float bj = bi[j];
    for (int r = 0; r < 8; ++r) {
        int nd = slot * 8 + r;
        float acc = bj;
#pragma unroll
        for (int k = 0; k < FIN; ++k) acc += xs[nd][k] * Ws[k * HD + j];
        acc = fmaxf(acc, 0.f);
        int o = (base + nd) * HD + j;
        h[o] = acc;
        unsigned short hv, lv; split_hl(acc, hv, lv);
        hhi[o] = hv; hlo[o] = lv;
    }
}

// ---------------- CSR build ----------------
__global__ __launch_bounds__(256) void k_hist(const int* __restrict__ a_ei, const int* __restrict__ e_ei,
                                              int* __restrict__ cnt) {
    int g = blockIdx.y;
    int gid = blockIdx.x * 256 + threadIdx.x;
    if (gid >= EE) return;
    const int* ei = g ? e_ei : a_ei;
    atomicAdd(&cnt[g * NN + ei[EE + gid]], 1);
}

__global__ __launch_bounds__(256) void k_scanA(const int* __restrict__ cnt, int* __restrict__ bsum) {
    int g = blockIdx.y, b = blockIdx.x, tid = threadIdx.x;
    int base = b * 1024 + tid * 4;
    int s = 0;
#pragma unroll
    for (int j = 0; j < 4; ++j) {
        int i = base + j;
        if (i < NN) s += cnt[g * NN + i];
    }
    __shared__ int lds[256];
    lds[tid] = s; __syncthreads();
    for (int o = 128; o > 0; o >>= 1) {
        if (tid < o) lds[tid] += lds[tid + o];
        __syncthreads();
    }
    if (tid == 0) bsum[g * SCB + b] = lds[0];
}

__global__ __launch_bounds__(64) void k_scanB(const int* __restrict__ bsum, int* __restrict__ bpre) {
    int tid = threadIdx.x;
    if (tid < 2) {
        int run = 0;
        for (int b = 0; b < SCB; ++b) { bpre[tid * SCB + b] = run; run += bsum[tid * SCB + b]; }
    }
}

__global__ __launch_bounds__(256) void k_scanC(const int* __restrict__ cnt, const int* __restrict__ bpre,
                                               int* __restrict__ cur,
                                               float* __restrict__ da, float* __restrict__ de) {
    int g = blockIdx.y, b = blockIdx.x, tid = threadIdx.x;
    float* dg = g ? de : da;
    int base = b * 1024 + tid * 4;
    int c[4]; int ts = 0;
#pragma unroll
    for (int j = 0; j < 4; ++j) {
        int i = base + j;
        c[j] = (i < NN) ? cnt[g * NN + i] : 0;
        ts += c[j];
    }
    __shared__ int lds[256];
    lds[tid] = ts; __syncthreads();
    for (int o = 1; o < 256; o <<= 1) {
        int v = (tid >= o) ? lds[tid - o] : 0;
        __syncthreads();
        lds[tid] += v;
        __syncthreads();
    }
    int run = lds[tid] - ts + bpre[g * SCB + b];
#pragma unroll
    for (int j = 0; j < 4; ++j) {
        int i = base + j;
        if (i < NN) { cur[g * NN + i] = run; dg[i] = (float)c[j]; run += c[j]; }
    }
}

__global__ __launch_bounds__(256) void k_scatter(
    const int* __restrict__ a_ei, const float* __restrict__ a_ea,
    const int* __restrict__ e_ei, const float* __restrict__ e_ea,
    int* __restrict__ cur, int4* __restrict__ es) {
    int g = blockIdx.y;
    int gid = blockIdx.x * 256 + threadIdx.x;
    if (gid >= EE) return;
    const int* ei = g ? e_ei : a_ei;
    const float* ea = g ? e_ea : a_ea;
    int src = ei[gid], tgt = ei[EE + gid];
    int slot = atomicAdd(&cur[g * NN + tgt], 1);
    es[(size_t)g * EE + slot] = make_int4(src, tgt,
        __float_as_int(ea[2 * gid]), __float_as_int(ea[2 * gid + 1]));
}

// ---------------- fused weight prep (hi/lo, n-major transposed) ----------------
__global__ __launch_bounds__(256) void k_prep_all(
    const float* __restrict__ aW1, const float* __restrict__ eW1,
    const float* __restrict__ aW2, const float* __restrict__ eW2,
    const float* __restrict__ cW,
    unsigned short* __restrict__ W1thi, unsigned short* __restrict__ W1tlo,
    unsigned short* __restrict__ W2thi, unsigned short* __restrict__ W2tlo,
    unsigned short* __restrict__ cWthi, unsigned short* __restrict__ cWtlo) {
    int i = blockIdx.x * 256 + threadIdx.x;
    unsigned short hv, lv;
    if (i < 131072) {                       // W1: 4 x [128n][256k]
        int s = i >> 15, r = i & 32767;
        const float* W = ((s < 2) ? aW1 : eW1) + (size_t)(s & 1) * 258 * HD;
        int n = r >> 8, k = r & 255;
        split_hl(W[k * HD + n], hv, lv);
        W1thi[i] = hv; W1tlo[i] = lv;
    } else if (i < 196608) {                // W2: 2 x [128n][256k] ([W2a;W2e])
        int j = i - 131072;
        int l = j >> 15, r = j & 32767;
        int n = r >> 8, k = r & 255;
        float v = (k < HD) ? aW2[(size_t)l * HD * HD + k * HD + n]
                           : eW2[(size_t)l * HD * HD + (k - HD) * HD + n];
        split_hl(v, hv, lv);
        W2thi[j] = hv; W2tlo[j] = lv;
    } else if (i < 229376) {                // cW: 2 x [128n][128k]
        int j = i - 196608;
        int l = j >> 14, r = j & 16383;
        int n = r >> 7, k = r & 127;
        split_hl(cW[(size_t)l * HD * HD + k * HD + n], hv, lv);
        cWthi[j] = hv; cWtlo[j] = lv;
    }
}

// ---------------- edge conv (sorted, segmented reduction) ----------------
__global__ __launch_bounds__(256) void k_edge(
    const unsigned short* __restrict__ hhi, const unsigned short* __restrict__ hlo,
    const int4* __restrict__ es,          // sorted by target: (src,tgt,ea0,ea1)
    const unsigned short* __restrict__ Whi, const unsigned short* __restrict__ Wlo,
    const float* __restrict__ W1full, const float* __restrict__ b1,
    float* __restrict__ zagg)
{
    __shared__ unsigned short m_hi[16 * 256], m_lo[16 * 256];
    __shared__ float z_s[16][129];
    __shared__ int   ts_s[16];
    __shared__ float ea_s[2][16];
    int tid = threadIdx.x;
    int wave = tid >> 6, lane = tid & 63;
    int l16 = lane & 15, quad = lane >> 4;
    int nb0 = wave * 2;
    int n0 = nb0 * 16 + l16, n1 = n0 + 16;

    f16x8 bhi[2][8], blo[2][8];
#pragma unroll
    for (int b = 0; b < 2; ++b) {
        int n = (nb0 + b) * 16 + l16;
        const unsigned short* ph = Whi + n * K1 + quad * 8;
        const unsigned short* pl = Wlo + n * K1 + quad * 8;
#pragma unroll
        for (int kt = 0; kt < 8; ++kt) {
            bhi[b][kt] = *(const f16x8*)(ph + kt * 32);
            blo[b][kt] = *(const f16x8*)(pl + kt * 32);
        }
    }
    float bias0 = b1[n0], bias1 = b1[n1];
    float w256_0 = W1full[256 * HD + n0], w257_0 = W1full[257 * HD + n0];
    float w256_1 = W1full[256 * HD + n1], w257_1 = W1full[257 * HD + n1];

    int le = tid >> 4, part = tid & 15;
    int xw = le & 7;     // write-side xor (row = le)
    int xr = l16 & 7;    // read-side xor (row = l16)

    for (int tile = blockIdx.x; tile < EE / 16; tile += gridDim.x) {
        __syncthreads();   // prev-iter readers (MFMA + segsum) done
        int4 q = es[tile * 16 + le];
        if (part == 0) {
            ts_s[le] = q.y;
            ea_s[0][le] = __int_as_float(q.z);
            ea_s[1][le] = __int_as_float(q.w);
        }
        size_t rb = (size_t)((part < 8) ? q.y : q.x) * HD + (part & 7) * 16;
        uint4 h0 = *(const uint4*)(hhi + rb);
        uint4 h1 = *(const uint4*)(hhi + rb + 8);
        uint4 l0 = *(const uint4*)(hlo + rb);
        uint4 l1 = *(const uint4*)(hlo + rb + 8);
        int c4a = (2 * part) ^ xw, c4b = (2 * part + 1) ^ xw;
        unsigned short* bh = m_hi + le * 256;
        unsigned short* bl = m_lo + le * 256;
        *(uint4*)(bh + c4a * 8) = h0; *(uint4*)(bh + c4b * 8) = h1;
        *(uint4*)(bl + c4a * 8) = l0; *(uint4*)(bl + c4b * 8) = l1;
        __syncthreads();

        f32x4 acc0 = {0,0,0,0}, acc1 = {0,0,0,0};
        f32x4 accL0 = {0,0,0,0}, accL1 = {0,0,0,0};
#pragma unroll
        for (int kt = 0; kt < 8; ++kt) {
            int c4 = (4 * kt + quad) ^ xr;
            f16x8 ah = *(const f16x8*)(m_hi + l16 * 256 + c4 * 8);
            f16x8 al = *(const f16x8*)(m_lo + l16 * 256 + c4 * 8);
            acc0  = MFMA16(ah, bhi[0][kt], acc0);
            acc1  = MFMA16(ah, bhi[1][kt], acc1);
            accL0 = MFMA16(ah, blo[0][kt], accL0);
            accL1 = MFMA16(ah, blo[1][kt], accL1);
            accL0 = MFMA16(al, bhi[0][kt], accL0);
            accL1 = MFMA16(al, bhi[1][kt], accL1);
        }

        // epilogue: bias + ea rank-2 + relu -> z_s
#pragma unroll
        for (int r = 0; r < 4; ++r) {
            int row = quad * 4 + r;
            float e0 = ea_s[0][row], e1 = ea_s[1][row];
            float z0 = fmaxf(acc0[r] + accL0[r] * INV_LOSCALE + bias0 + e0 * w256_0 + e1 * w257_0, 0.f);
            float z1 = fmaxf(acc1[r] + accL1[r] * INV_LOSCALE + bias1 + e0 * w256_1 + e1 * w257_1, 0.f);
            z_s[row][n0] = z0;
            z_s[row][n1] = z1;
        }
        __syncthreads();

        // segmented sum over 16 sorted rows; interior segments -> plain store
        if (tid < 128) {
            int c = tid;
            float run = z_s[0][c];
            int tp = ts_s[0];
            bool open0 = true;    // segment touches row 0 -> may continue in prev tile
#pragma unroll
            for (int r = 1; r < 16; ++r) {
                int t = ts_s[r];
                float v = z_s[r][c];
                if (t == tp) { run += v; }
                else {
                    float* p = zagg + (size_t)tp * HD + c;
                    if (open0) atomicAdd(p, run);
                    else       *p = run;       // fully interior: exclusive owner
                    run = v; tp = t; open0 = false;
                }
            }
            atomicAdd(zagg + (size_t)tp * HD + c, run);  // touches row 15
        }
    }
}

// ---------------- node update (hi/lo MFMA) ----------------
__global__ __launch_bounds__(256) void k_node(
    float* __restrict__ h,
    unsigned short* __restrict__ hhi, unsigned short* __restrict__ hlo,
    const float* __restrict__ za, const float* __restrict__ ze,
    const float* __restrict__ da, const float* __restrict__ de,
    const unsigned short* __restrict__ W2hi, const unsigned short* __restrict__ W2lo,
    const float* __restrict__ b2a, const float* __restrict__ b2e,
    const float* __restrict__ g, const float* __restrict__ bln,
    const unsigned short* __restrict__ cWhi, const unsigned short* __restrict__ cWlo,
    const float* __restrict__ cb)
{
    __shared__ unsigned short a_hi[16][264], a_lo[16][264];
    __shared__ float t1_s[16][132];
    __shared__ unsigned short u_hi[16][136], u_lo[16][136];
    __shared__ float g_s[HD], b_s[HD];
    int tid = threadIdx.x;
    int wave = tid >> 6, lane = tid & 63;
    int l16 = lane & 15, quad = lane >> 4;
    int nb0 = wave * 2;
    int n0 = nb0 * 16 + l16, n1 = n0 + 16;

    if (tid < HD) { g_s[tid] = g[tid]; b_s[tid] = bln[tid]; }

    f16x8 b2h[2][8], b2l[2][8], bch[2][4], bcl[2][4];
#pragma unroll
    for (int b = 0; b < 2; ++b) {
        int n = (nb0 + b) * 16 + l16;
        const unsigned short* p2h = W2hi + n * 256 + quad * 8;
        const unsigned short* p2l = W2lo + n * 256 + quad * 8;
#pragma unroll
        for (int kt = 0; kt < 8; ++kt) {
            b2h[b][kt] = *(const f16x8*)(p2h + kt * 32);
            b2l[b][kt] = *(const f16x8*)(p2l + kt * 32);
        }
        const unsigned short* pch = cWhi + n * 128 + quad * 8;
        const unsigned short* pcl = cWlo + n * 128 + quad * 8;
#pragma unroll
        for (int kt = 0; kt < 4; ++kt) {
            bch[b][kt] = *(const f16x8*)(pch + kt * 32);
            bcl[b][kt] = *(const f16x8*)(pcl + kt * 32);
        }
    }
    float vb2a0 = b2a[n0], vb2a1 = b2a[n1];
    float vb2e0 = b2e[n0], vb2e1 = b2e[n1];
    float vcb0 = cb[n0], vcb1 = cb[n1];

    int base = blockIdx.x * 16;
    int nd = tid >> 4, part = tid & 15;

    {
        const float* sp = ((part < 8) ? za : ze) + (size_t)(base + nd) * HD + (part & 7) * 16;
        union { unsigned short s[16]; uint4 q[2]; } Hv, Lv;
#pragma unroll
        for (int i = 0; i < 4; ++i) {
            float4 f = ((const float4*)sp)[i];
            split_hl(f.x, Hv.s[4*i+0], Lv.s[4*i+0]);
            split_hl(f.y, Hv.s[4*i+1], Lv.s[4*i+1]);
            split_hl(f.z, Hv.s[4*i+2], Lv.s[4*i+2]);
            split_hl(f.w, Hv.s[4*i+3], Lv.s[4*i+3]);
        }
        int ko = part * 16;
        *(uint4*)&a_hi[nd][ko] = Hv.q[0]; *(uint4*)&a_hi[nd][ko + 8] = Hv.q[1];
        *(uint4*)&a_lo[nd][ko] = Lv.q[0]; *(uint4*)&a_lo[nd][ko + 8] = Lv.q[1];
    }
    __syncthreads();

    f32x4 acc0 = {0,0,0,0}, acc1 = {0,0,0,0}, accL0 = {0,0,0,0}, accL1 = {0,0,0,0};
#pragma unroll
    for (int kt = 0; kt < 8; ++kt) {
        f16x8 ah = *(const f16x8*)&a_hi[l16][kt * 32 + quad * 8];
        f16x8 al = *(const f16x8*)&a_lo[l16][kt * 32 + quad * 8];
        acc0  = MFMA16(ah, b2h[0][kt], acc0);
        acc1  = MFMA16(ah, b2h[1][kt], acc1);
        accL0 = MFMA16(ah, b2l[0][kt], accL0);
        accL1 = MFMA16(ah, b2l[1][kt], accL1);
        accL0 = MFMA16(al, b2h[0][kt], accL0);
        accL1 = MFMA16(al, b2h[1][kt], accL1);
    }
#pragma unroll
    for (int r = 0; r < 4; ++r) {
        int ndl = quad * 4 + r;
        int go = (base + ndl) * HD;
        float dav = da[base + ndl], dev = de[base + ndl];
        t1_s[ndl][n0] = acc0[r] + accL0[r] * INV_LOSCALE + h[go + n0] + dav * vb2a0 + dev * vb2e0;
        t1_s[ndl][n1] = acc1[r] + accL1[r] * INV_LOSCALE + h[go + n1] + dav * vb2a1 + dev * vb2e1;
    }
    __syncthreads();

    float v[8]; float s = 0.f, ss = 0.f;
#pragma unroll
    for (int i = 0; i < 8; ++i) { v[i] = t1_s[nd][part * 8 + i]; s += v[i]; ss += v[i] * v[i]; }
#pragma unroll
    for (int m = 1; m < 16; m <<= 1) { s += __shfl_xor(s, m); ss += __shfl_xor(ss, m); }
    float mu = s * (1.f / HD);
    float var = ss * (1.f / HD) - mu * mu;
    float inv = rsqrtf(var + 1e-5f);
    {
        union { unsigned short s[8]; uint4 q; } Hu, Lu;
#pragma unroll
        for (int i = 0; i < 8; ++i) {
            int c = part * 8 + i;
            float u = (v[i] - mu) * inv * g_s[c] + b_s[c];
            t1_s[nd][c] = u;
            split_hl(u, Hu.s[i], Lu.s[i]);
        }
        *(uint4*)&u_hi[nd][part * 8] = Hu.q;
        *(uint4*)&u_lo[nd][part * 8] = Lu.q;
    }
    __syncthreads();

    f32x4 c0 = {0,0,0,0}, c1 = {0,0,0,0}, cL0 = {0,0,0,0}, cL1 = {0,0,0,0};
#pragma unroll
    for (int kt = 0; kt < 4; ++kt) {
        f16x8 ah = *(const f16x8*)&u_hi[l16][kt * 32 + quad * 8];
        f16x8 al = *(const f16x8*)&u_lo[l16][kt * 32 + quad * 8];
        c0  = MFMA16(ah, bch[0][kt], c0);
        c1  = MFMA16(ah, bch[1][kt], c1);
        cL0 = MFMA16(ah, bcl[0][kt], cL0);
        cL1 = MFMA16(ah, bcl[1][kt], cL1);
        cL0 = MFMA16(al, bch[0][kt], cL0);
        cL1 = MFMA16(al, bch[1][kt], cL1);
    }
#pragma unroll
    for (int r = 0; r < 4; ++r) {
        int ndl = quad * 4 + r;
        int go = (base + ndl) * HD;
        float u0 = t1_s[ndl][n0], u1 = t1_s[ndl][n1];
        float r0 = fmaxf(c0[r] + cL0[r] * INV_LOSCALE + vcb0, 0.f);
        float r1 = fmaxf(c1[r] + cL1[r] * INV_LOSCALE + vcb1, 0.f);
        float o0 = u0 + r0, o1 = u1 + r1;
        h[go + n0] = o0; h[go + n1] = o1;
        unsigned short hv, lv;
        split_hl(o0, hv, lv); hhi[go + n0] = hv; hlo[go + n0] = lv;
        split_hl(o1, hv, lv); hhi[go + n1] = hv; hlo[go + n1] = lv;
    }
}

extern "C" void kernel_launch(void* const* d_in, const int* in_sizes, int n_in,
                              void* d_out, int out_size, void* d_ws, size_t ws_size,
                              hipStream_t stream) {
    const float* x    = (const float*)d_in[0];
    const int*   a_ei = (const int*)d_in[1];
    const float* a_ea = (const float*)d_in[2];
    const int*   e_ei = (const int*)d_in[3];
    const float* e_ea = (const float*)d_in[4];
    const float* W_in = (const float*)d_in[5];
    const float* b_in = (const float*)d_in[6];
    const float* aW1  = (const float*)d_in[7];
    const float* ab1  = (const float*)d_in[8];
    const float* aW2  = (const float*)d_in[9];
    const float* ab2  = (const float*)d_in[10];
    const float* eW1  = (const float*)d_in[11];
    const float* eb1  = (const float*)d_in[12];
    const float* eW2  = (const float*)d_in[13];
    const float* eb2  = (const float*)d_in[14];
    const float* ln_g = (const float*)d_in[15];
    const float* ln_b = (const float*)d_in[16];
    const float* cW   = (const float*)d_in[17];
    const float* cb   = (const float*)d_in[18];
    float* h = (float*)d_out;

    char* ws = (char*)d_ws;
    int4* es = (int4*)ws;                        ws += (size_t)2 * EE * 16;
    unsigned short* hhi = (unsigned short*)ws;   ws += (size_t)NN * HD * 2;
    unsigned short* hlo = (unsigned short*)ws;   ws += (size_t)NN * HD * 2;
    float* zagg_a = (float*)ws;                  ws += (size_t)NN * HD * 4;
    float* zagg_e = (float*)ws;                  ws += (size_t)NN * HD * 4;
    unsigned short* W1thi = (unsigned short*)ws; ws += (size_t)4 * HD * K1 * 2;
    unsigned short* W1tlo = (unsigned short*)ws; ws += (size_t)4 * HD * K1 * 2;
    unsigned short* W2thi = (unsigned short*)ws; ws += (size_t)2 * HD * 256 * 2;
    unsigned short* W2tlo = (unsigned short*)ws; ws += (size_t)2 * HD * 256 * 2;
    unsigned short* cWthi = (unsigned short*)ws; ws += (size_t)2 * HD * HD * 2;
    unsigned short* cWtlo = (unsigned short*)ws; ws += (size_t)2 * HD * HD * 2;
    int* cnt = (int*)ws;                         ws += (size_t)2 * NN * 4;
    int* cur = (int*)ws;                         ws += (size_t)2 * NN * 4;
    int* bsum = (int*)ws;                        ws += 800;
    int* bpre = (int*)ws;                        ws += 800;
    float* da = (float*)ws;                      ws += (size_t)NN * 4;
    float* de = (float*)ws;                      ws += (size_t)NN * 4;

    k_input_proj<<<NN / 16, 256, 0, stream>>>(x, W_in, b_in, h, hhi, hlo);

    // CSR build (once per launch; reused by both layers)
    hipMemsetAsync(cnt, 0, (size_t)2 * NN * 4, stream);
    dim3 ge((EE + 255) / 256, 2);
    k_hist<<<ge, 256, 0, stream>>>(a_ei, e_ei, cnt);
    dim3 gs(SCB, 2);
    k_scanA<<<gs, 256, 0, stream>>>(cnt, bsum);
    k_scanB<<<1, 64, 0, stream>>>(bsum, bpre);
    k_scanC<<<gs, 256, 0, stream>>>(cnt, bpre, cur, da, de);
    k_scatter<<<ge, 256, 0, stream>>>(a_ei, a_ea, e_ei, e_ea, cur, es);

    k_prep_all<<<896, 256, 0, stream>>>(aW1, eW1, aW2, eW2, cW,
                                        W1thi, W1tlo, W2thi, W2tlo, cWthi, cWtlo);

    const int W1SZ = (2 * HD + 2) * HD;
    for (int l = 0; l < 2; ++l) {
        hipMemsetAsync(zagg_a, 0, (size_t)2 * NN * HD * 4, stream);  // zagg_a + zagg_e adjacent
        k_edge<<<4096, 256, 0, stream>>>(hhi, hlo, es,
            W1thi + (0 + l) * HD * K1, W1tlo + (0 + l) * HD * K1,
            aW1 + (size_t)l * W1SZ, ab1 + l * HD, zagg_a);
        k_edge<<<4096, 256, 0, stream>>>(hhi, hlo, es + (size_t)EE,
            W1thi + (2 + l) * HD * K1, W1tlo + (2 + l) * HD * K1,
            eW1 + (size_t)l * W1SZ, eb1 + l * HD, zagg_e);
        k_node<<<NN / 16, 256, 0, stream>>>(h, hhi, hlo, zagg_a, zagg_e, da, de,
            W2thi + l * HD * 256, W2tlo + l * HD * 256, ab2 + l * HD, eb2 + l * HD,
            ln_g + l * HD, ln_b + l * HD,
            cWthi + l * HD * HD, cWtlo + l * HD * HD, cb + l * HD);
    }
}

// Round 7
// 1432.121 us; speedup vs baseline: 9.6837x; 1.1222x over previous
//
#include <hip/hip_runtime.h>

#define NN 100000
#define EE 600000
#define FIN 39
#define HD 128
#define K1 256          // W1t layout K (k<128 = target half, k>=128 = source half)
#define NT32 (EE / 32)  // 18750 edge tiles of 32
#define LOSCALE 4096.0f
#define INV_LOSCALE (1.0f / 4096.0f)
#define SCB 98          // scan blocks per graph: 98*1024 >= NN

typedef _Float16 f16x8 __attribute__((ext_vector_type(8)));
typedef __attribute__((ext_vector_type(4))) float f32x4;

#define MFMA16(a, b, c) __builtin_amdgcn_mfma_f32_16x16x32_f16((a), (b), (c), 0, 0, 0)

__device__ __forceinline__ void split_hl(float x, unsigned short& hi, unsigned short& lo) {
    union { _Float16 h; unsigned short u; } a, b;
    a.h = (_Float16)x;
    float r = (x - (float)a.h) * LOSCALE;   // scaled residual stays fp16-normal
    b.h = (_Float16)r;
    hi = a.u; lo = b.u;
}

// ---------------- input projection: h = relu(x @ W_in + b_in), fp32; emit hi/lo ----------------
__global__ __launch_bounds__(256) void k_input_proj(
    const float* __restrict__ x, const float* __restrict__ Wi,
    const float* __restrict__ bi, float* __restrict__ h,
    unsigned short* __restrict__ hhi, unsigned short* __restrict__ hlo)
{
    __shared__ float Ws[FIN * HD];
    __shared__ float xs[16][FIN + 1];
    int tid = threadIdx.x;
    for (int i = tid; i < FIN * HD; i += 256) Ws[i] = Wi[i];
    int base = blockIdx.x * 16;
    for (int i = tid; i < 16 * FIN; i += 256) {
        int nd = i / FIN, k = i - nd * FIN;
        xs[nd][k] = x[(size_t)(base + nd) * FIN + k];
    }
    __syncthreads();
    int j = tid & 127, slot = tid >> 7;
    float bj = bi[j];
    for (int r = 0; r < 8; ++r) {
        int nd = slot * 8 + r;
        float acc = bj;
#pragma unroll
        for (int k = 0; k < FIN; ++k) acc += xs[nd][k] * Ws[k * HD + j];
        acc = fmaxf(acc, 0.f);
        int o = (base + nd) * HD + j;
        h[o] = acc;
        unsigned short hv, lv; split_hl(acc, hv, lv);
        hhi[o] = hv; hlo[o] = lv;
    }
}

// ---------------- CSR build ----------------
__global__ __launch_bounds__(256) void k_hist(const int* __restrict__ a_ei, const int* __restrict__ e_ei,
                                              int* __restrict__ cnt) {
    int g = blockIdx.y;
    int gid = blockIdx.x * 256 + threadIdx.x;
    if (gid >= EE) return;
    const int* ei = g ? e_ei : a_ei;
    atomicAdd(&cnt[g * NN + ei[EE + gid]], 1);
}

__global__ __launch_bounds__(256) void k_scanA(const int* __restrict__ cnt, int* __restrict__ bsum) {
    int g = blockIdx.y, b = blockIdx.x, tid = threadIdx.x;
    int base = b * 1024 + tid * 4;
    int s = 0;
#pragma unroll
    for (int j = 0; j < 4; ++j) {
        int i = base + j;
        if (i < NN) s += cnt[g * NN + i];
    }
    __shared__ int lds[256];
    lds[tid] = s; __syncthreads();
    for (int o = 128; o > 0; o >>= 1) {
        if (tid < o) lds[tid] += lds[tid + o];
        __syncthreads();
    }
    if (tid == 0) bsum[g * SCB + b] = lds[0];
}

__global__ __launch_bounds__(64) void k_scanB(const int* __restrict__ bsum, int* __restrict__ bpre) {
    int tid = threadIdx.x;
    if (tid < 2) {
        int run = 0;
        for (int b = 0; b < SCB; ++b) { bpre[tid * SCB + b] = run; run += bsum[tid * SCB + b]; }
    }
}

__global__ __launch_bounds__(256) void k_scanC(const int* __restrict__ cnt, const int* __restrict__ bpre,
                                               int* __restrict__ cur,
                                               float* __restrict__ da, float* __restrict__ de) {
    int g = blockIdx.y, b = blockIdx.x, tid = threadIdx.x;
    float* dg = g ? de : da;
    int base = b * 1024 + tid * 4;
    int c[4]; int ts = 0;
#pragma unroll
    for (int j = 0; j < 4; ++j) {
        int i = base + j;
        c[j] = (i < NN) ? cnt[g * NN + i] : 0;
        ts += c[j];
    }
    __shared__ int lds[256];
    lds[tid] = ts; __syncthreads();
    for (int o = 1; o < 256; o <<= 1) {
        int v = (tid >= o) ? lds[tid - o] : 0;
        __syncthreads();
        lds[tid] += v;
        __syncthreads();
    }
    int run = lds[tid] - ts + bpre[g * SCB + b];
#pragma unroll
    for (int j = 0; j < 4; ++j) {
        int i = base + j;
        if (i < NN) { cur[g * NN + i] = run; dg[i] = (float)c[j]; run += c[j]; }
    }
}

__global__ __launch_bounds__(256) void k_scatter(
    const int* __restrict__ a_ei, const float* __restrict__ a_ea,
    const int* __restrict__ e_ei, const float* __restrict__ e_ea,
    int* __restrict__ cur, int4* __restrict__ es) {
    int g = blockIdx.y;
    int gid = blockIdx.x * 256 + threadIdx.x;
    if (gid >= EE) return;
    const int* ei = g ? e_ei : a_ei;
    const float* ea = g ? e_ea : a_ea;
    int src = ei[gid], tgt = ei[EE + gid];
    int slot = atomicAdd(&cur[g * NN + tgt], 1);
    es[(size_t)g * EE + slot] = make_int4(src, tgt,
        __float_as_int(ea[2 * gid]), __float_as_int(ea[2 * gid + 1]));
}

// ---------------- fused weight prep (hi/lo, n-major transposed) ----------------
__global__ __launch_bounds__(256) void k_prep_all(
    const float* __restrict__ aW1, const float* __restrict__ eW1,
    const float* __restrict__ aW2, const float* __restrict__ eW2,
    const float* __restrict__ cW,
    unsigned short* __restrict__ W1thi, unsigned short* __restrict__ W1tlo,
    unsigned short* __restrict__ W2thi, unsigned short* __restrict__ W2tlo,
    unsigned short* __restrict__ cWthi, unsigned short* __restrict__ cWtlo) {
    int i = blockIdx.x * 256 + threadIdx.x;
    unsigned short hv, lv;
    if (i < 131072) {                       // W1: 4 x [128n][256k]
        int s = i >> 15, r = i & 32767;
        const float* W = ((s < 2) ? aW1 : eW1) + (size_t)(s & 1) * 258 * HD;
        int n = r >> 8, k = r & 255;
        split_hl(W[k * HD + n], hv, lv);
        W1thi[i] = hv; W1tlo[i] = lv;
    } else if (i < 196608) {                // W2: 2 x [128n][256k] ([W2a;W2e])
        int j = i - 131072;
        int l = j >> 15, r = j & 32767;
        int n = r >> 8, k = r & 255;
        float v = (k < HD) ? aW2[(size_t)l * HD * HD + k * HD + n]
                           : eW2[(size_t)l * HD * HD + (k - HD) * HD + n];
        split_hl(v, hv, lv);
        W2thi[j] = hv; W2tlo[j] = lv;
    } else if (i < 229376) {                // cW: 2 x [128n][128k]
        int j = i - 196608;
        int l = j >> 14, r = j & 16383;
        int n = r >> 7, k = r & 127;
        split_hl(cW[(size_t)l * HD * HD + k * HD + n], hv, lv);
        cWthi[j] = hv; cWtlo[j] = lv;
    }
}

// ---------------- target context: c[t][n] = sum_k<128 h_t[k] W1[k][n] + b1[n] ----------------
__global__ __launch_bounds__(256) void k_ctx(
    const unsigned short* __restrict__ hhi, const unsigned short* __restrict__ hlo,
    const unsigned short* __restrict__ Whi, const unsigned short* __restrict__ Wlo,
    const float* __restrict__ b1, float* __restrict__ cc)
{
    __shared__ __align__(16) unsigned short a_hi[16 * 128], a_lo[16 * 128];
    int tid = threadIdx.x;
    int wave = tid >> 6, lane = tid & 63;
    int l16 = lane & 15, quad = lane >> 4;
    int n0 = wave * 32 + l16, n1 = n0 + 16;

    f16x8 bh[2][4], bl[2][4];
#pragma unroll
    for (int b = 0; b < 2; ++b) {
        int n = wave * 32 + b * 16 + l16;
        const unsigned short* ph = Whi + n * K1 + quad * 8;   // target half: k 0..127
        const unsigned short* pl = Wlo + n * K1 + quad * 8;
#pragma unroll
        for (int kt = 0; kt < 4; ++kt) {
            bh[b][kt] = *(const f16x8*)(ph + kt * 32);
            bl[b][kt] = *(const f16x8*)(pl + kt * 32);
        }
    }
    float vb0 = b1[n0], vb1 = b1[n1];

    int base = blockIdx.x * 16;
    int nd = tid >> 4, part = tid & 15;
    {
        int pm = part & 7;
        const unsigned short* hsel = (part < 8) ? hhi : hlo;
        unsigned short* msel = ((part < 8) ? a_hi : a_lo) + nd * 128;
        const uint4* gp = (const uint4*)(hsel + (size_t)(base + nd) * HD + pm * 16);
        uint4 v0 = gp[0], v1 = gp[1];
        int c0 = (2 * pm) ^ nd, c1 = (2 * pm + 1) ^ nd;
        *(uint4*)(msel + c0 * 8) = v0;
        *(uint4*)(msel + c1 * 8) = v1;
    }
    __syncthreads();

    f32x4 h0 = {0,0,0,0}, h1 = {0,0,0,0}, L0 = {0,0,0,0}, L1 = {0,0,0,0};
#pragma unroll
    for (int kt = 0; kt < 4; ++kt) {
        int ch = ((kt * 4 + quad) ^ l16) * 8;
        f16x8 ah = *(const f16x8*)(a_hi + l16 * 128 + ch);
        f16x8 al = *(const f16x8*)(a_lo + l16 * 128 + ch);
        h0 = MFMA16(ah, bh[0][kt], h0);
        h1 = MFMA16(ah, bh[1][kt], h1);
        L0 = MFMA16(ah, bl[0][kt], L0);
        L0 = MFMA16(al, bh[0][kt], L0);
        L1 = MFMA16(ah, bl[1][kt], L1);
        L1 = MFMA16(al, bh[1][kt], L1);
    }
#pragma unroll
    for (int r = 0; r < 4; ++r) {
        int rr = quad * 4 + r;
        float* cp = cc + (size_t)(base + rr) * HD;
        cp[n0] = h0[r] + L0[r] * INV_LOSCALE + vb0;
        cp[n1] = h1[r] + L1[r] * INV_LOSCALE + vb1;
    }
}

// ---------------- edge conv (sorted, src-only K=128, M=32 tiles, prefetch pipeline) ----------------
__global__ __launch_bounds__(256, 3) void k_edge(
    const unsigned short* __restrict__ hhi, const unsigned short* __restrict__ hlo,
    const int4* __restrict__ es,          // sorted by target: (src,tgt,ea0,ea1)
    const unsigned short* __restrict__ Whi, const unsigned short* __restrict__ Wlo, // [128][256]
    const float* __restrict__ W1full,     // rows 256/257 for ea
    const float* __restrict__ cctx,       // [node][128]: tgt half + b1
    float* __restrict__ zagg)
{
    __shared__ __align__(16) unsigned short m_hi[32 * 128];
    __shared__ __align__(16) unsigned short m_lo[32 * 128];
    __shared__ float z_s[32][132];
    __shared__ int   ts_s[32];
    __shared__ float ea_s[2][32];

    int tid = threadIdx.x;
    int wave = tid >> 6, lane = tid & 63;
    int l16 = lane & 15, quad = lane >> 4;
    int n0 = wave * 32 + l16, n1 = n0 + 16;

    // persistent B fragments: source half of W1 (k = 128..255)
    f16x8 bhi[2][4], blo[2][4];
#pragma unroll
    for (int b = 0; b < 2; ++b) {
        int n = wave * 32 + b * 16 + l16;
        const unsigned short* ph = Whi + n * K1 + 128 + quad * 8;
        const unsigned short* pl = Wlo + n * K1 + 128 + quad * 8;
#pragma unroll
        for (int kt = 0; kt < 4; ++kt) {
            bhi[b][kt] = *(const f16x8*)(ph + kt * 32);
            blo[b][kt] = *(const f16x8*)(pl + kt * 32);
        }
    }
    float w256_0 = W1full[256 * HD + n0], w257_0 = W1full[257 * HD + n0];
    float w256_1 = W1full[256 * HD + n1], w257_1 = W1full[257 * HD + n1];

    int row = tid >> 3, part = tid & 7;   // 32 rows x 8 parts (64B each)
    int pm = part & 3;
    const unsigned short* hsel = (part < 4) ? hhi : hlo;
    unsigned short* msel = ((part < 4) ? m_hi : m_lo) + row * 128;
    int sw = row & 15;

    int stride = gridDim.x;
    int tile = blockIdx.x;

    // prologue: q_cur(tile), gather G(tile), q_nxt(tile+stride)
    int4 q_cur = es[tile * 32 + row];
    uint4 G0, G1, G2, G3;
    {
        const uint4* gp = (const uint4*)(hsel + (size_t)q_cur.x * HD + pm * 32);
        G0 = gp[0]; G1 = gp[1]; G2 = gp[2]; G3 = gp[3];
    }
    int tn = tile + stride;
    int4 q_nxt = es[(tn < NT32 ? tn : tile) * 32 + row];

    for (; tile < NT32; tile += stride) {
        __syncthreads();                    // A: prev-iter readers done
        if (part == 0) {
            ts_s[row] = q_cur.y;
            ea_s[0][row] = __int_as_float(q_cur.z);
            ea_s[1][row] = __int_as_float(q_cur.w);
        }
        {
            int c0 = (pm * 4 + 0) ^ sw, c1 = (pm * 4 + 1) ^ sw;
            int c2 = (pm * 4 + 2) ^ sw, c3 = (pm * 4 + 3) ^ sw;
            *(uint4*)(msel + c0 * 8) = G0;
            *(uint4*)(msel + c1 * 8) = G1;
            *(uint4*)(msel + c2 * 8) = G2;
            *(uint4*)(msel + c3 * 8) = G3;
        }
        __syncthreads();                    // B: staged

        // prefetch next tile's rows + es two ahead (hidden behind MFMA/epilogue)
        {
            const uint4* gp = (const uint4*)(hsel + (size_t)q_nxt.x * HD + pm * 32);
            G0 = gp[0]; G1 = gp[1]; G2 = gp[2]; G3 = gp[3];
        }
        int t2 = tile + 2 * stride;
        int4 q_tmp = es[(t2 < NT32 ? t2 : tile) * 32 + row];

        f32x4 aH0 = {0,0,0,0}, aH1 = {0,0,0,0}, aH2 = {0,0,0,0}, aH3 = {0,0,0,0};
        f32x4 aL0 = {0,0,0,0}, aL1 = {0,0,0,0}, aL2 = {0,0,0,0}, aL3 = {0,0,0,0};
#pragma unroll
        for (int kt = 0; kt < 4; ++kt) {
            int ch = ((kt * 4 + quad) ^ l16) * 8;
            f16x8 a0h = *(const f16x8*)(m_hi + l16 * 128 + ch);
            f16x8 a0l = *(const f16x8*)(m_lo + l16 * 128 + ch);
            f16x8 a1h = *(const f16x8*)(m_hi + (l16 + 16) * 128 + ch);
            f16x8 a1l = *(const f16x8*)(m_lo + (l16 + 16) * 128 + ch);
            aH0 = MFMA16(a0h, bhi[0][kt], aH0);
            aH1 = MFMA16(a0h, bhi[1][kt], aH1);
            aH2 = MFMA16(a1h, bhi[0][kt], aH2);
            aH3 = MFMA16(a1h, bhi[1][kt], aH3);
            aL0 = MFMA16(a0h, blo[0][kt], aL0);
            aL0 = MFMA16(a0l, bhi[0][kt], aL0);
            aL1 = MFMA16(a0h, blo[1][kt], aL1);
            aL1 = MFMA16(a0l, bhi[1][kt], aL1);
            aL2 = MFMA16(a1h, blo[0][kt], aL2);
            aL2 = MFMA16(a1l, bhi[0][kt], aL2);
            aL3 = MFMA16(a1h, blo[1][kt], aL3);
            aL3 = MFMA16(a1l, bhi[1][kt], aL3);
        }

        // epilogue: + c[tgt] + ea rank-2, relu -> z_s
#pragma unroll
        for (int r = 0; r < 4; ++r) {
            int r0 = quad * 4 + r, r1 = r0 + 16;
            int t0 = ts_s[r0], t1 = ts_s[r1];
            float e00 = ea_s[0][r0], e01 = ea_s[1][r0];
            float e10 = ea_s[0][r1], e11 = ea_s[1][r1];
            const float* cp0 = cctx + (size_t)t0 * HD;
            const float* cp1 = cctx + (size_t)t1 * HD;
            z_s[r0][n0] = fmaxf(aH0[r] + aL0[r] * INV_LOSCALE + cp0[n0] + e00 * w256_0 + e01 * w257_0, 0.f);
            z_s[r0][n1] = fmaxf(aH1[r] + aL1[r] * INV_LOSCALE + cp0[n1] + e00 * w256_1 + e01 * w257_1, 0.f);
            z_s[r1][n0] = fmaxf(aH2[r] + aL2[r] * INV_LOSCALE + cp1[n0] + e10 * w256_0 + e11 * w257_0, 0.f);
            z_s[r1][n1] = fmaxf(aH3[r] + aL3[r] * INV_LOSCALE + cp1[n1] + e10 * w256_1 + e11 * w257_1, 0.f);
        }
        __syncthreads();                    // C: z_s ready

        // segmented sum over 32 sorted rows
        if (tid < 128) {
            int c = tid;
            float run = z_s[0][c];
            int tp = ts_s[0];
            bool open0 = true;
#pragma unroll
            for (int r = 1; r < 32; ++r) {
                int t = ts_s[r];
                float v = z_s[r][c];
                if (t == tp) { run += v; }
                else {
                    float* p = zagg + (size_t)tp * HD + c;
                    if (open0) atomicAdd(p, run);
                    else       *p = run;
                    run = v; tp = t; open0 = false;
                }
            }
            atomicAdd(zagg + (size_t)tp * HD + c, run);
        }

        q_cur = q_nxt; q_nxt = q_tmp;
    }
}

// ---------------- node update (hi/lo MFMA) ----------------
__global__ __launch_bounds__(256) void k_node(
    float* __restrict__ h,
    unsigned short* __restrict__ hhi, unsigned short* __restrict__ hlo,
    const float* __restrict__ za, const float* __restrict__ ze,
    const float* __restrict__ da, const float* __restrict__ de,
    const unsigned short* __restrict__ W2hi, const unsigned short* __restrict__ W2lo,
    const float* __restrict__ b2a, const float* __restrict__ b2e,
    const float* __restrict__ g, const float* __restrict__ bln,
    const unsigned short* __restrict__ cWhi, const unsigned short* __restrict__ cWlo,
    const float* __restrict__ cb)
{
    __shared__ __align__(16) unsigned short a_hi[16][264], a_lo[16][264];
    __shared__ float t1_s[16][132];
    __shared__ __align__(16) unsigned short u_hi[16][136], u_lo[16][136];
    __shared__ float g_s[HD], b_s[HD];
    int tid = threadIdx.x;
    int wave = tid >> 6, lane = tid & 63;
    int l16 = lane & 15, quad = lane >> 4;
    int nb0 = wave * 2;
    int n0 = nb0 * 16 + l16, n1 = n0 + 16;

    if (tid < HD) { g_s[tid] = g[tid]; b_s[tid] = bln[tid]; }

    f16x8 b2h[2][8], b2l[2][8], bch[2][4], bcl[2][4];
#pragma unroll
    for (int b = 0; b < 2; ++b) {
        int n = (nb0 + b) * 16 + l16;
        const unsigned short* p2h = W2hi + n * 256 + quad * 8;
        const unsigned short* p2l = W2lo + n * 256 + quad * 8;
#pragma unroll
        for (int kt = 0; kt < 8; ++kt) {
            b2h[b][kt] = *(const f16x8*)(p2h + kt * 32);
            b2l[b][kt] = *(const f16x8*)(p2l + kt * 32);
        }
        const unsigned short* pch = cWhi + n * 128 + quad * 8;
        const unsigned short* pcl = cWlo + n * 128 + quad * 8;
#pragma unroll
        for (int kt = 0; kt < 4; ++kt) {
            bch[b][kt] = *(const f16x8*)(pch + kt * 32);
            bcl[b][kt] = *(const f16x8*)(pcl + kt * 32);
        }
    }
    float vb2a0 = b2a[n0], vb2a1 = b2a[n1];
    float vb2e0 = b2e[n0], vb2e1 = b2e[n1];
    float vcb0 = cb[n0], vcb1 = cb[n1];

    int base = blockIdx.x * 16;
    int nd = tid >> 4, part = tid & 15;

    {
        const float* sp = ((part < 8) ? za : ze) + (size_t)(base + nd) * HD + (part & 7) * 16;
        union { unsigned short s[16]; uint4 q[2]; } Hv, Lv;
#pragma unroll
        for (int i = 0; i < 4; ++i) {
            float4 f = ((const float4*)sp)[i];
            split_hl(f.x, Hv.s[4*i+0], Lv.s[4*i+0]);
            split_hl(f.y, Hv.s[4*i+1], Lv.s[4*i+1]);
            split_hl(f.z, Hv.s[4*i+2], Lv.s[4*i+2]);
            split_hl(f.w, Hv.s[4*i+3], Lv.s[4*i+3]);
        }
        int ko = part * 16;
        *(uint4*)&a_hi[nd][ko] = Hv.q[0]; *(uint4*)&a_hi[nd][ko + 8] = Hv.q[1];
        *(uint4*)&a_lo[nd][ko] = Lv.q[0]; *(uint4*)&a_lo[nd][ko + 8] = Lv.q[1];
    }
    __syncthreads();

    f32x4 acc0 = {0,0,0,0}, acc1 = {0,0,0,0}, accL0 = {0,0,0,0}, accL1 = {0,0,0,0};
#pragma unroll
    for (int kt = 0; kt < 8; ++kt) {
        f16x8 ah = *(const f16x8*)&a_hi[l16][kt * 32 + quad * 8];
        f16x8 al = *(const f16x8*)&a_lo[l16][kt * 32 + quad * 8];
        acc0  = MFMA16(ah, b2h[0][kt], acc0);
        acc1  = MFMA16(ah, b2h[1][kt], acc1);
        accL0 = MFMA16(ah, b2l[0][kt], accL0);
        accL1 = MFMA16(ah, b2l[1][kt], accL1);
        accL0 = MFMA16(al, b2h[0][kt], accL0);
        accL1 = MFMA16(al, b2h[1][kt], accL1);
    }
#pragma unroll
    for (int r = 0; r < 4; ++r) {
        int ndl = quad * 4 + r;
        int go = (base + ndl) * HD;
        float dav = da[base + ndl], dev = de[base + ndl];
        t1_s[ndl][n0] = acc0[r] + accL0[r] * INV_LOSCALE + h[go + n0] + dav * vb2a0 + dev * vb2e0;
        t1_s[ndl][n1] = acc1[r] + accL1[r] * INV_LOSCALE + h[go + n1] + dav * vb2a1 + dev * vb2e1;
    }
    __syncthreads();

    float v[8]; float s = 0.f, ss = 0.f;
#pragma unroll
    for (int i = 0; i < 8; ++i) { v[i] = t1_s[nd][part * 8 + i]; s += v[i]; ss += v[i] * v[i]; }
#pragma unroll
    for (int m = 1; m < 16; m <<= 1) { s += __shfl_xor(s, m); ss += __shfl_xor(ss, m); }
    float mu = s * (1.f / HD);
    float var = ss * (1.f / HD) - mu * mu;
    float inv = rsqrtf(var + 1e-5f);
    {
        union { unsigned short s[8]; uint4 q; } Hu, Lu;
#pragma unroll
        for (int i = 0; i < 8; ++i) {
            int c = part * 8 + i;
            float u = (v[i] - mu) * inv * g_s[c] + b_s[c];
            t1_s[nd][c] = u;
            split_hl(u, Hu.s[i], Lu.s[i]);
        }
        *(uint4*)&u_hi[nd][part * 8] = Hu.q;
        *(uint4*)&u_lo[nd][part * 8] = Lu.q;
    }
    __syncthreads();

    f32x4 c0 = {0,0,0,0}, c1 = {0,0,0,0}, cL0 = {0,0,0,0}, cL1 = {0,0,0,0};
#pragma unroll
    for (int kt = 0; kt < 4; ++kt) {
        f16x8 ah = *(const f16x8*)&u_hi[l16][kt * 32 + quad * 8];
        f16x8 al = *(const f16x8*)&u_lo[l16][kt * 32 + quad * 8];
        c0  = MFMA16(ah, bch[0][kt], c0);
        c1  = MFMA16(ah, bch[1][kt], c1);
        cL0 = MFMA16(ah, bcl[0][kt], cL0);
        cL1 = MFMA16(ah, bcl[1][kt], cL1);
        cL0 = MFMA16(al, bch[0][kt], cL0);
        cL1 = MFMA16(al, bch[1][kt], cL1);
    }
#pragma unroll
    for (int r = 0; r < 4; ++r) {
        int ndl = quad * 4 + r;
        int go = (base + ndl) * HD;
        float u0 = t1_s[ndl][n0], u1 = t1_s[ndl][n1];
        float r0 = fmaxf(c0[r] + cL0[r] * INV_LOSCALE + vcb0, 0.f);
        float r1 = fmaxf(c1[r] + cL1[r] * INV_LOSCALE + vcb1, 0.f);
        float o0 = u0 + r0, o1 = u1 + r1;
        h[go + n0] = o0; h[go + n1] = o1;
        unsigned short hv, lv;
        split_hl(o0, hv, lv); hhi[go + n0] = hv; hlo[go + n0] = lv;
        split_hl(o1, hv, lv); hhi[go + n1] = hv; hlo[go + n1] = lv;
    }
}

extern "C" void kernel_launch(void* const* d_in, const int* in_sizes, int n_in,
                              void* d_out, int out_size, void* d_ws, size_t ws_size,
                              hipStream_t stream) {
    const float* x    = (const float*)d_in[0];
    const int*   a_ei = (const int*)d_in[1];
    const float* a_ea = (const float*)d_in[2];
    const int*   e_ei = (const int*)d_in[3];
    const float* e_ea = (const float*)d_in[4];
    const float* W_in = (const float*)d_in[5];
    const float* b_in = (const float*)d_in[6];
    const float* aW1  = (const float*)d_in[7];
    const float* ab1  = (const float*)d_in[8];
    const float* aW2  = (const float*)d_in[9];
    const float* ab2  = (const float*)d_in[10];
    const float* eW1  = (const float*)d_in[11];
    const float* eb1  = (const float*)d_in[12];
    const float* eW2  = (const float*)d_in[13];
    const float* eb2  = (const float*)d_in[14];
    const float* ln_g = (const float*)d_in[15];
    const float* ln_b = (const float*)d_in[16];
    const float* cW   = (const float*)d_in[17];
    const float* cb   = (const float*)d_in[18];
    float* h = (float*)d_out;

    // ---- workspace layout, total ~226 MB (R6's 278 MB crashed; suspect ws_size limit) ----
    char* ws = (char*)d_ws;
    int4* es = (int4*)ws;                        ws += (size_t)2 * EE * 16;     // 19.2 MB
    unsigned short* hhi = (unsigned short*)ws;   ws += (size_t)NN * HD * 2;     // 25.6 MB
    unsigned short* hlo = (unsigned short*)ws;   ws += (size_t)NN * HD * 2;     // 25.6 MB
    float* zagg_a = (float*)ws;                  ws += (size_t)NN * HD * 4;     // 51.2 MB
    float* zagg_e = (float*)ws;                  ws += (size_t)NN * HD * 4;     // 51.2 MB
    float* ctx = (float*)ws;                     ws += (size_t)NN * HD * 4;     // 51.2 MB (shared per graph)
    unsigned short* W1thi = (unsigned short*)ws; ws += (size_t)4 * HD * K1 * 2;
    unsigned short* W1tlo = (unsigned short*)ws; ws += (size_t)4 * HD * K1 * 2;
    unsigned short* W2thi = (unsigned short*)ws; ws += (size_t)2 * HD * 256 * 2;
    unsigned short* W2tlo = (unsigned short*)ws; ws += (size_t)2 * HD * 256 * 2;
    unsigned short* cWthi = (unsigned short*)ws; ws += (size_t)2 * HD * HD * 2;
    unsigned short* cWtlo = (unsigned short*)ws; ws += (size_t)2 * HD * HD * 2;
    float* da = (float*)ws;                      ws += (size_t)NN * 4;
    float* de = (float*)ws;                      ws += (size_t)NN * 4;
    // CSR-build scratch aliased into ctx (dead before first k_ctx writes ctx)
    int* cnt = (int*)ctx;
    int* cur = cnt + 2 * NN;
    int* bsum = cur + 2 * NN;
    int* bpre = bsum + 2 * SCB;

    k_input_proj<<<NN / 16, 256, 0, stream>>>(x, W_in, b_in, h, hhi, hlo);

    // CSR build (once per launch; reused by both layers)
    hipMemsetAsync(cnt, 0, (size_t)2 * NN * 4, stream);
    dim3 ge((EE + 255) / 256, 2);
    k_hist<<<ge, 256, 0, stream>>>(a_ei, e_ei, cnt);
    dim3 gs(SCB, 2);
    k_scanA<<<gs, 256, 0, stream>>>(cnt, bsum);
    k_scanB<<<1, 64, 0, stream>>>(bsum, bpre);
    k_scanC<<<gs, 256, 0, stream>>>(cnt, bpre, cur, da, de);
    k_scatter<<<ge, 256, 0, stream>>>(a_ei, a_ea, e_ei, e_ea, cur, es);

    k_prep_all<<<896, 256, 0, stream>>>(aW1, eW1, aW2, eW2, cW,
                                        W1thi, W1tlo, W2thi, W2tlo, cWthi, cWtlo);

    const int W1SZ = (2 * HD + 2) * HD;
    for (int l = 0; l < 2; ++l) {
        hipMemsetAsync(zagg_a, 0, (size_t)2 * NN * HD * 4, stream);  // zagg_a + zagg_e adjacent
        k_ctx<<<NN / 16, 256, 0, stream>>>(hhi, hlo,
            W1thi + (0 + l) * HD * K1, W1tlo + (0 + l) * HD * K1, ab1 + l * HD, ctx);
        k_edge<<<2048, 256, 0, stream>>>(hhi, hlo, es,
            W1thi + (0 + l) * HD * K1, W1tlo + (0 + l) * HD * K1,
            aW1 + (size_t)l * W1SZ, ctx, zagg_a);
        k_ctx<<<NN / 16, 256, 0, stream>>>(hhi, hlo,
            W1thi + (2 + l) * HD * K1, W1tlo + (2 + l) * HD * K1, eb1 + l * HD, ctx);
        k_edge<<<2048, 256, 0, stream>>>(hhi, hlo, es + (size_t)EE,
            W1thi + (2 + l) * HD * K1, W1tlo + (2 + l) * HD * K1,
            eW1 + (size_t)l * W1SZ, ctx, zagg_e);
        k_node<<<NN / 16, 256, 0, stream>>>(h, hhi, hlo, zagg_a, zagg_e, da, de,
            W2thi + l * HD * 256, W2tlo + l * HD * 256, ab2 + l * HD, eb2 + l * HD,
            ln_g + l * HD, ln_b + l * HD,
            cWthi + l * HD * HD, cWtlo + l * HD * HD, cb + l * HD);
    }
}